// Round 2
// baseline (15288.779 us; speedup 1.0000x reference)
//
#include <hip/hip_runtime.h>

// Masked GRU (RNNStateEncoder), T=256, N=128, D=H=1024.
// Persistent cooperative-style kernel: 64 WGs, manual grid barrier per step.
// bf16 MFMA 16x16x32 with A-side hi/lo split for precision; W in plain bf16.

#define TSTEPS 256
#define NBATCH 128
#define DDIM   1024
#define HDIM   1024

typedef short  bf16x8 __attribute__((ext_vector_type(8)));
typedef float  f32x4  __attribute__((ext_vector_type(4)));

// ---- ws layout (bytes) ----
#define BAR_CTR_OFF  0
#define BAR_GEN_OFF  4
#define MFLAG_OFF    8
#define WIH_OFF      512
#define WHH_OFF      (512 + 6291456)            // 6291968
#define HF_OFF       (WHH_OFF + 6291456)        // 12583424 : float h[2][128*1024]
#define HHI_OFF      (HF_OFF + 1048576)         // 13632000 : ushort hhi[2][128*1024]
#define HLO_OFF      (HHI_OFF + 524288)         // 14156288 : ushort hlo[2][128*1024]

__device__ __forceinline__ unsigned short f2bf(float f) {
    union { float f; unsigned u; } v; v.f = f;
    unsigned r = v.u + 0x7FFFu + ((v.u >> 16) & 1u);   // RNE
    return (unsigned short)(r >> 16);
}
__device__ __forceinline__ float bf2f(unsigned short h) {
    union { unsigned u; float f; } v; v.u = ((unsigned)h) << 16;
    return v.f;
}

__device__ __forceinline__ float mask_val(const void* m, int fmt, int idx) {
    if (fmt == 0) return ((const unsigned char*)m)[idx] ? 1.f : 0.f;
    if (fmt == 1) return ((const int*)m)[idx] ? 1.f : 0.f;
    return (((const float*)m)[idx] != 0.f) ? 1.f : 0.f;
}

// ---- detect mask dtype: 0 = bool bytes, 1 = int32, 2 = float32 ----
__global__ void detect_mask(const unsigned char* __restrict__ m8, int* __restrict__ flag) {
    __shared__ int s_ones, s_c01, s_cf;
    if (threadIdx.x == 0) { s_ones = 0; s_c01 = 0; s_cf = 0; }
    __syncthreads();
    int ones = 0;
    for (int i = threadIdx.x; i < 4096; i += 256) ones += (m8[i] == 1);
    int c01 = 0, cf = 0;
    const unsigned* m32 = (const unsigned*)m8;
    for (int i = threadIdx.x; i < 1024; i += 256) {
        unsigned v = m32[i];
        c01 += (v <= 1u);
        cf  += (v == 0u || v == 0x3F800000u);
    }
    atomicAdd(&s_ones, ones); atomicAdd(&s_c01, c01); atomicAdd(&s_cf, cf);
    __syncthreads();
    if (threadIdx.x == 0) *flag = (s_ones > 2048) ? 0 : ((s_c01 >= s_cf) ? 1 : 2);
}

// ---- convert both weight matrices to bf16 (row-major (3072,1024)) ----
__global__ void conv_w(const float* __restrict__ wih, const float* __restrict__ whh,
                       unsigned short* __restrict__ wih_b, unsigned short* __restrict__ whh_b) {
    size_t i = ((size_t)blockIdx.x * 256 + threadIdx.x) * 4;
    if (i >= (size_t)3145728) return;
    float4 a = *(const float4*)(wih + i);
    ushort4 ra; ra.x = f2bf(a.x); ra.y = f2bf(a.y); ra.z = f2bf(a.z); ra.w = f2bf(a.w);
    *(ushort4*)(wih_b + i) = ra;
    float4 b = *(const float4*)(whh + i);
    ushort4 rb; rb.x = f2bf(b.x); rb.y = f2bf(b.y); rb.z = f2bf(b.z); rb.w = f2bf(b.w);
    *(ushort4*)(whh_b + i) = rb;
}

// ---- init h0 (pre-masked with m[0]) into buffer 0 ----
__global__ void init_h(const float* __restrict__ h0, const unsigned char* __restrict__ masks,
                       const int* __restrict__ flag,
                       float* __restrict__ hf, unsigned short* __restrict__ hhi,
                       unsigned short* __restrict__ hlo) {
    int i = (blockIdx.x * 256 + threadIdx.x) * 4;
    if (i >= NBATCH * HDIM) return;
    int fmt = *flag;
    int n = i >> 10;
    float m = mask_val(masks, fmt, n);   // t=0 mask: idx = 0*128 + n
    float4 a = *(const float4*)(h0 + i);
    float v[4] = { a.x * m, a.y * m, a.z * m, a.w * m };
#pragma unroll
    for (int q = 0; q < 4; ++q) {
        hf[i + q] = v[q];
        unsigned short hi = f2bf(v[q]);
        hhi[i + q] = hi;
        hlo[i + q] = f2bf(v[q] - bf2f(hi));
    }
}

// ---- main persistent GRU kernel: 64 WGs x 256 threads ----
__launch_bounds__(256)
__global__ void gru_main(const float* __restrict__ x,
                         const unsigned char* __restrict__ masks,
                         const float* __restrict__ bih, const float* __restrict__ bhh,
                         const unsigned short* __restrict__ wih,
                         const unsigned short* __restrict__ whh,
                         float* __restrict__ out,
                         float* __restrict__ hf,
                         unsigned short* __restrict__ hhi,
                         unsigned short* __restrict__ hlo,
                         int* __restrict__ bar_ctr, int* __restrict__ bar_gen,
                         const int* __restrict__ mflag) {
    const int bid  = blockIdx.x;
    const int xcd  = bid & 7;
    const int slot = bid >> 3;
    const int cb   = xcd * 2 + (slot >> 2);   // col-block 0..15 (64 h-cols each)
    const int rb   = slot & 3;                // row-block 0..3  (32 samples each)
    const int tid  = threadIdx.x;
    const int wid  = tid >> 6;
    const int lane = tid & 63;
    const int l15  = lane & 15;
    const int l4   = lane >> 4;
    const int mfmt = *mflag;

    __shared__ float xp_l[32][196];
    __shared__ float hp_l[32][196];

    // gate-col base for this wave's 3 local col-tiles (ct = wid*3+c in [0,12))
    int gbase[3];
#pragma unroll
    for (int c = 0; c < 3; ++c) {
        int ct = wid * 3 + c;
        gbase[c] = (ct >> 2) * 1024 + cb * 64 + (ct & 3) * 16;
    }

    for (int t = 0; t < TSTEPS; ++t) {
        const int cur = t & 1, nxt = cur ^ 1;

        f32x4 accx[2][3], acch[2][3];
        const f32x4 zz = {0.f, 0.f, 0.f, 0.f};
#pragma unroll
        for (int rt = 0; rt < 2; ++rt)
#pragma unroll
            for (int c = 0; c < 3; ++c) { accx[rt][c] = zz; acch[rt][c] = zz; }

        const unsigned short* hhi_c = hhi + (size_t)cur * (NBATCH * HDIM);
        const unsigned short* hlo_c = hlo + (size_t)cur * (NBATCH * HDIM);

        for (int kk = 0; kk < DDIM; kk += 32) {
            const int kb = kk + l4 * 8;
            bf16x8 axh[2], axl[2], ahh[2], ahl[2];
#pragma unroll
            for (int rt = 0; rt < 2; ++rt) {
                const int row = rb * 32 + rt * 16 + l15;
                const float* px = x + ((size_t)(t * NBATCH + row)) * DDIM + kb;
                float4 f0 = *(const float4*)px;
                float4 f1 = *(const float4*)(px + 4);
                float v[8] = { f0.x, f0.y, f0.z, f0.w, f1.x, f1.y, f1.z, f1.w };
#pragma unroll
                for (int q = 0; q < 8; ++q) {
                    unsigned short hi = f2bf(v[q]);
                    axh[rt][q] = (short)hi;
                    axl[rt][q] = (short)f2bf(v[q] - bf2f(hi));
                }
                const size_t hoff = (size_t)row * HDIM + kb;
                ahh[rt] = *(const bf16x8*)(hhi_c + hoff);
                ahl[rt] = *(const bf16x8*)(hlo_c + hoff);
            }
#pragma unroll
            for (int c = 0; c < 3; ++c) {
                const size_t wrow = (size_t)(gbase[c] + l15) * 1024 + kb;
                const bf16x8 bx = *(const bf16x8*)(wih + wrow);
                const bf16x8 bh = *(const bf16x8*)(whh + wrow);
#pragma unroll
                for (int rt = 0; rt < 2; ++rt) {
                    accx[rt][c] = __builtin_amdgcn_mfma_f32_16x16x32_bf16(axh[rt], bx, accx[rt][c], 0, 0, 0);
                    accx[rt][c] = __builtin_amdgcn_mfma_f32_16x16x32_bf16(axl[rt], bx, accx[rt][c], 0, 0, 0);
                    acch[rt][c] = __builtin_amdgcn_mfma_f32_16x16x32_bf16(ahh[rt], bh, acch[rt][c], 0, 0, 0);
                    acch[rt][c] = __builtin_amdgcn_mfma_f32_16x16x32_bf16(ahl[rt], bh, acch[rt][c], 0, 0, 0);
                }
            }
        }

        // accumulators -> LDS. D layout: col = lane&15, row = (lane>>4)*4 + i
#pragma unroll
        for (int c = 0; c < 3; ++c) {
            const int ct = wid * 3 + c;
#pragma unroll
            for (int rt = 0; rt < 2; ++rt) {
#pragma unroll
                for (int i = 0; i < 4; ++i) {
                    const int row = rt * 16 + l4 * 4 + i;
                    const int col = ct * 16 + l15;
                    xp_l[row][col] = accx[rt][c][i];
                    hp_l[row][col] = acch[rt][c][i];
                }
            }
        }
        __syncthreads();

        // gates + h update: 32 rows x 64 h-cols = 2048 outputs, 8 per thread
#pragma unroll
        for (int u = 0; u < 8; ++u) {
            const int o   = u * 256 + tid;
            const int row = o >> 6;
            const int j   = o & 63;
            const int nIdx = rb * 32 + row;
            const int gj   = cb * 64 + j;
            const float xr = xp_l[row][j],       hr = hp_l[row][j];
            const float xz = xp_l[row][64 + j],  hz = hp_l[row][64 + j];
            const float xn = xp_l[row][128 + j], hn = hp_l[row][128 + j];
            const float ar = xr + hr + bih[gj] + bhh[gj];
            const float az = xz + hz + bih[1024 + gj] + bhh[1024 + gj];
            const float rg = 1.f / (1.f + __expf(-ar));
            const float zg = 1.f / (1.f + __expf(-az));
            const float nc = tanhf(xn + bih[2048 + gj] + rg * (hn + bhh[2048 + gj]));
            const float hold = hf[(size_t)cur * (NBATCH * HDIM) + (size_t)nIdx * HDIM + gj];
            const float hnew = (1.f - zg) * nc + zg * hold;
            out[((size_t)t * NBATCH + nIdx) * HDIM + gj] = hnew;
            if (t == TSTEPS - 1) {
                out[(size_t)TSTEPS * NBATCH * HDIM + (size_t)nIdx * HDIM + gj] = hnew;
            } else {
                const float m  = mask_val(masks, mfmt, (t + 1) * NBATCH + nIdx);
                const float hm = hnew * m;
                const size_t ho = (size_t)nxt * (NBATCH * HDIM) + (size_t)nIdx * HDIM + gj;
                hf[ho] = hm;
                const unsigned short hi = f2bf(hm);
                hhi[ho] = hi;
                hlo[ho] = f2bf(hm - bf2f(hi));
            }
        }

        // grid barrier (skip after final step)
        if (t != TSTEPS - 1) {
            __syncthreads();
            if (tid == 0) {
                __threadfence();
                int a = __hip_atomic_fetch_add(bar_ctr, 1, __ATOMIC_ACQ_REL, __HIP_MEMORY_SCOPE_AGENT);
                if (a == (int)gridDim.x - 1) {
                    __hip_atomic_store(bar_ctr, 0, __ATOMIC_RELAXED, __HIP_MEMORY_SCOPE_AGENT);
                    __hip_atomic_store(bar_gen, t + 1, __ATOMIC_RELEASE, __HIP_MEMORY_SCOPE_AGENT);
                } else {
                    while (__hip_atomic_load(bar_gen, __ATOMIC_ACQUIRE, __HIP_MEMORY_SCOPE_AGENT) < t + 1) {
                        __builtin_amdgcn_s_sleep(16);
                    }
                }
            }
            __syncthreads();
        }
    }
}

extern "C" void kernel_launch(void* const* d_in, const int* in_sizes, int n_in,
                              void* d_out, int out_size, void* d_ws, size_t ws_size,
                              hipStream_t stream) {
    const float* x      = (const float*)d_in[0];
    const float* hidden = (const float*)d_in[1];
    const unsigned char* masks = (const unsigned char*)d_in[2];
    const float* wih    = (const float*)d_in[3];
    const float* whh    = (const float*)d_in[4];
    const float* bih    = (const float*)d_in[5];
    const float* bhh    = (const float*)d_in[6];
    float* out = (float*)d_out;
    char*  ws  = (char*)d_ws;

    hipMemsetAsync(ws, 0, 512, stream);
    detect_mask<<<1, 256, 0, stream>>>(masks, (int*)(ws + MFLAG_OFF));
    conv_w<<<3072, 256, 0, stream>>>(wih, whh,
                                     (unsigned short*)(ws + WIH_OFF),
                                     (unsigned short*)(ws + WHH_OFF));
    init_h<<<128, 256, 0, stream>>>(hidden, masks, (const int*)(ws + MFLAG_OFF),
                                    (float*)(ws + HF_OFF),
                                    (unsigned short*)(ws + HHI_OFF),
                                    (unsigned short*)(ws + HLO_OFF));
    gru_main<<<64, 256, 0, stream>>>(x, masks, bih, bhh,
                                     (const unsigned short*)(ws + WIH_OFF),
                                     (const unsigned short*)(ws + WHH_OFF),
                                     out,
                                     (float*)(ws + HF_OFF),
                                     (unsigned short*)(ws + HHI_OFF),
                                     (unsigned short*)(ws + HLO_OFF),
                                     (int*)(ws + BAR_CTR_OFF), (int*)(ws + BAR_GEN_OFF),
                                     (const int*)(ws + MFLAG_OFF));
}

// Round 3
// 5900.370 us; speedup vs baseline: 2.5912x; 2.5912x over previous
//
#include <hip/hip_runtime.h>

// Masked GRU (RNNStateEncoder), T=256, N=128, D=H=1024.
// Fast path: Phase A = parallel x-projection GEMM (bf16 MFMA, LDS dbuf),
//            Phase B = sequential h-GEMM with W_hh LDS-resident, 128 WGs,
//                      manual grid barrier per step, h split hi/lo bf16.
// Fallback (ws too small): round-2 monolithic persistent kernel.

#define TSTEPS 256
#define NBATCH 128
#define DDIM   1024
#define HDIM   1024

typedef short  bf16x8 __attribute__((ext_vector_type(8)));
typedef float  f32x4  __attribute__((ext_vector_type(4)));

// ---- ws layout (bytes) ----
#define BAR_CTR_OFF  0
#define BAR_GEN_OFF  4
#define MFLAG_OFF    8
#define WIH_OFF      512
#define WHH_OFF      (512 + 6291456)            // 6291968
#define HF_OFF       (WHH_OFF + 6291456)        // 12583424 : float h[2][128*1024] (fallback only)
#define HHI_OFF      (HF_OFF + 1048576)         // 13632000 : ushort hhi[2][128*1024]
#define HLO_OFF      (HHI_OFF + 524288)         // 14156288 : ushort hlo[2][128*1024]
#define XB_OFF       (HLO_OFF + 524288)         // 14680576 : ushort xb[32768*1024]
#define XP_OFF       (XB_OFF + 67108864)        // 81789440 : ushort xp[32768*3072]
#define WS_NEED      (XP_OFF + 201326592ull)    // 283116032

__device__ __forceinline__ unsigned short f2bf(float f) {
    union { float f; unsigned u; } v; v.f = f;
    unsigned r = v.u + 0x7FFFu + ((v.u >> 16) & 1u);   // RNE
    return (unsigned short)(r >> 16);
}
__device__ __forceinline__ float bf2f(unsigned short h) {
    union { unsigned u; float f; } v; v.u = ((unsigned)h) << 16;
    return v.f;
}

__device__ __forceinline__ float mask_val(const void* m, int fmt, int idx) {
    if (fmt == 0) return ((const unsigned char*)m)[idx] ? 1.f : 0.f;
    if (fmt == 1) return ((const int*)m)[idx] ? 1.f : 0.f;
    return (((const float*)m)[idx] != 0.f) ? 1.f : 0.f;
}

// ---- detect mask dtype: 0 = bool bytes, 1 = int32, 2 = float32 ----
__global__ void detect_mask(const unsigned char* __restrict__ m8, int* __restrict__ flag) {
    __shared__ int s_ones, s_c01, s_cf;
    if (threadIdx.x == 0) { s_ones = 0; s_c01 = 0; s_cf = 0; }
    __syncthreads();
    int ones = 0;
    for (int i = threadIdx.x; i < 4096; i += 256) ones += (m8[i] == 1);
    int c01 = 0, cf = 0;
    const unsigned* m32 = (const unsigned*)m8;
    for (int i = threadIdx.x; i < 1024; i += 256) {
        unsigned v = m32[i];
        c01 += (v <= 1u);
        cf  += (v == 0u || v == 0x3F800000u);
    }
    atomicAdd(&s_ones, ones); atomicAdd(&s_c01, c01); atomicAdd(&s_cf, cf);
    __syncthreads();
    if (threadIdx.x == 0) *flag = (s_ones > 2048) ? 0 : ((s_c01 >= s_cf) ? 1 : 2);
}

// ---- convert both weight matrices to bf16 (row-major (3072,1024)) ----
__global__ void conv_w(const float* __restrict__ wih, const float* __restrict__ whh,
                       unsigned short* __restrict__ wih_b, unsigned short* __restrict__ whh_b) {
    size_t i = ((size_t)blockIdx.x * 256 + threadIdx.x) * 4;
    if (i >= (size_t)3145728) return;
    float4 a = *(const float4*)(wih + i);
    ushort4 ra; ra.x = f2bf(a.x); ra.y = f2bf(a.y); ra.z = f2bf(a.z); ra.w = f2bf(a.w);
    *(ushort4*)(wih_b + i) = ra;
    float4 b = *(const float4*)(whh + i);
    ushort4 rb; rb.x = f2bf(b.x); rb.y = f2bf(b.y); rb.z = f2bf(b.z); rb.w = f2bf(b.w);
    *(ushort4*)(whh_b + i) = rb;
}

// ---- convert x (32768x1024 f32) to bf16 ----
__global__ void conv_x(const float* __restrict__ x, unsigned short* __restrict__ xb) {
    size_t i = ((size_t)blockIdx.x * 256 + threadIdx.x) * 8;
    float4 a = *(const float4*)(x + i);
    float4 b = *(const float4*)(x + i + 4);
    bf16x8 r;
    r[0] = (short)f2bf(a.x); r[1] = (short)f2bf(a.y); r[2] = (short)f2bf(a.z); r[3] = (short)f2bf(a.w);
    r[4] = (short)f2bf(b.x); r[5] = (short)f2bf(b.y); r[6] = (short)f2bf(b.z); r[7] = (short)f2bf(b.w);
    *(bf16x8*)(xb + i) = r;
}

// ---- init h0 (pre-masked with m[0]) into buffer 0 ----
__global__ void init_h(const float* __restrict__ h0, const unsigned char* __restrict__ masks,
                       const int* __restrict__ flag,
                       float* __restrict__ hf, unsigned short* __restrict__ hhi,
                       unsigned short* __restrict__ hlo) {
    int i = (blockIdx.x * 256 + threadIdx.x) * 4;
    if (i >= NBATCH * HDIM) return;
    int fmt = *flag;
    int n = i >> 10;
    float m = mask_val(masks, fmt, n);
    float4 a = *(const float4*)(h0 + i);
    float v[4] = { a.x * m, a.y * m, a.z * m, a.w * m };
#pragma unroll
    for (int q = 0; q < 4; ++q) {
        hf[i + q] = v[q];
        unsigned short hi = f2bf(v[q]);
        hhi[i + q] = hi;
        hlo[i + q] = f2bf(v[q] - bf2f(hi));
    }
}

// ============== Phase A: xp = xb @ W_ih^T + b_ih  (bf16 out) ==============
// C tile 128x128, K=1024, BK=32. 4 waves, each a 64x64 quadrant (4x4 MFMA tiles).
// Double-buffered LDS, reg-staged, XOR swizzle ((row&7)<<4) on both sides.
__launch_bounds__(256)
__global__ void xproj_gemm(const unsigned short* __restrict__ xb,
                           const unsigned short* __restrict__ wih_b,
                           const float* __restrict__ bih,
                           unsigned short* __restrict__ xp) {
    const int m0 = blockIdx.x * 128;     // 0..255 -> rows
    const int n0 = blockIdx.y * 128;     // 0..23  -> gate cols
    const int tid  = threadIdx.x;
    const int wave = tid >> 6;
    const int lane = tid & 63;
    const int l15  = lane & 15;
    const int l4   = lane >> 4;
    const int wr   = wave >> 1;          // quadrant row (0..1)
    const int wc   = wave & 1;           // quadrant col (0..1)

    __shared__ __align__(16) unsigned short Asm[2][4096];   // [128][32]
    __shared__ __align__(16) unsigned short Bsm[2][4096];

    // per-thread staging indices: chunks q = tid, tid+256 (16B each)
    const int row0 = tid >> 2, kc0 = tid & 3;          // chunk 0: row0, kc0
    // chunk 1: row0+64, kc0
    const int wb0 = ((row0 * 64 + kc0 * 16) ^ ((row0 & 7) << 4));
    const int wb1 = (((row0 + 64) * 64 + kc0 * 16) ^ (((row0 + 64) & 7) << 4));

    f32x4 acc[4][4];
    const f32x4 zz = {0.f, 0.f, 0.f, 0.f};
#pragma unroll
    for (int m = 0; m < 4; ++m)
#pragma unroll
        for (int n = 0; n < 4; ++n) acc[m][n] = zz;

    // prologue: stage kt=0 into buf0
    {
        bf16x8 a0 = *(const bf16x8*)(xb + (size_t)(m0 + row0) * 1024 + kc0 * 8);
        bf16x8 a1 = *(const bf16x8*)(xb + (size_t)(m0 + row0 + 64) * 1024 + kc0 * 8);
        bf16x8 b0 = *(const bf16x8*)(wih_b + (size_t)(n0 + row0) * 1024 + kc0 * 8);
        bf16x8 b1 = *(const bf16x8*)(wih_b + (size_t)(n0 + row0 + 64) * 1024 + kc0 * 8);
        *(bf16x8*)((char*)Asm[0] + wb0) = a0;
        *(bf16x8*)((char*)Asm[0] + wb1) = a1;
        *(bf16x8*)((char*)Bsm[0] + wb0) = b0;
        *(bf16x8*)((char*)Bsm[0] + wb1) = b1;
    }
    __syncthreads();

    for (int kt = 0; kt < 32; ++kt) {
        const int cur = kt & 1;
        bf16x8 a0, a1, b0, b1;
        const bool pre = (kt < 31);
        if (pre) {
            const int kk = (kt + 1) * 32;
            a0 = *(const bf16x8*)(xb + (size_t)(m0 + row0) * 1024 + kk + kc0 * 8);
            a1 = *(const bf16x8*)(xb + (size_t)(m0 + row0 + 64) * 1024 + kk + kc0 * 8);
            b0 = *(const bf16x8*)(wih_b + (size_t)(n0 + row0) * 1024 + kk + kc0 * 8);
            b1 = *(const bf16x8*)(wih_b + (size_t)(n0 + row0 + 64) * 1024 + kk + kc0 * 8);
        }
        // compute from cur
        bf16x8 af[4], bf[4];
#pragma unroll
        for (int m = 0; m < 4; ++m) {
            const int r = wr * 64 + m * 16 + l15;
            af[m] = *(const bf16x8*)((char*)Asm[cur] + ((r * 64 + l4 * 16) ^ ((r & 7) << 4)));
        }
#pragma unroll
        for (int n = 0; n < 4; ++n) {
            const int r = wc * 64 + n * 16 + l15;
            bf[n] = *(const bf16x8*)((char*)Bsm[cur] + ((r * 64 + l4 * 16) ^ ((r & 7) << 4)));
        }
#pragma unroll
        for (int m = 0; m < 4; ++m)
#pragma unroll
            for (int n = 0; n < 4; ++n)
                acc[m][n] = __builtin_amdgcn_mfma_f32_16x16x32_bf16(af[m], bf[n], acc[m][n], 0, 0, 0);
        if (pre) {
            const int nxt = cur ^ 1;
            *(bf16x8*)((char*)Asm[nxt] + wb0) = a0;
            *(bf16x8*)((char*)Asm[nxt] + wb1) = a1;
            *(bf16x8*)((char*)Bsm[nxt] + wb0) = b0;
            *(bf16x8*)((char*)Bsm[nxt] + wb1) = b1;
        }
        __syncthreads();
    }

    // epilogue: add bih, convert, store
#pragma unroll
    for (int n = 0; n < 4; ++n) {
        const int col = n0 + wc * 64 + n * 16 + l15;
        const float bv = bih[col];
#pragma unroll
        for (int m = 0; m < 4; ++m) {
#pragma unroll
            for (int i = 0; i < 4; ++i) {
                const int row = m0 + wr * 64 + m * 16 + l4 * 4 + i;
                xp[(size_t)row * 3072 + col] = f2bf(acc[m][n][i] + bv);
            }
        }
    }
}

// ============== Phase B: sequential GRU steps ==============
// 128 WGs = 64 col-blocks (16 h-cols) x 2 row-blocks (64 rows). 256 thr (4 waves).
// W_hh slice (48 gate-rows x 1024) LDS-resident, XOR-swizzled. h split hi/lo bf16.
__launch_bounds__(256)
__global__ void gru_seq(const unsigned short* __restrict__ xp,
                        const unsigned char* __restrict__ masks,
                        const int* __restrict__ mflag,
                        const float* __restrict__ bhh,
                        const unsigned short* __restrict__ whh_b,
                        const float* __restrict__ h0,
                        float* __restrict__ out,
                        unsigned short* __restrict__ hhi,
                        unsigned short* __restrict__ hlo,
                        int* __restrict__ bar_ctr, int* __restrict__ bar_gen) {
    const int bid = blockIdx.x;
    const int cb  = bid >> 1;          // 0..63
    const int rb  = bid & 1;           // 0..1
    const int tid = threadIdx.x;
    const int wave = tid >> 6;         // = rt (0..3)
    const int lane = tid & 63;
    const int l15  = lane & 15;
    const int l4   = lane >> 4;
    const int mfmt = *mflag;

    __shared__ __align__(16) unsigned short Wl[49152];   // 48 rows x 1024, swizzled

    // load W_hh slice into LDS (once)
#pragma unroll
    for (int it = 0; it < 24; ++it) {
        const int c  = it * 256 + tid;       // 0..6143
        const int sr = c >> 7;               // 0..47
        const int kc = c & 127;              // 0..127 (16B chunks)
        const int g  = (sr >> 4) * 1024 + cb * 16 + (sr & 15);
        bf16x8 v = *(const bf16x8*)(whh_b + (size_t)g * 1024 + kc * 8);
        const int byte = (sr * 2048 + kc * 16) ^ ((sr & 7) << 4);
        *(bf16x8*)((char*)Wl + byte) = v;
    }

    // static ownership: lane holds rows n_i = rb*64 + wave*16 + l4*4 + i, col j
    const int j = cb * 16 + l15;
    const int nb0 = rb * 64 + wave * 16 + l4 * 4;
    const float bhr = bhh[j], bhz = bhh[1024 + j], bhn = bhh[2048 + j];

    float hold[4];
#pragma unroll
    for (int i = 0; i < 4; ++i) {
        const int n = nb0 + i;
        hold[i] = h0[(size_t)n * 1024 + j] * mask_val(masks, mfmt, n);
    }
    const int an = rb * 64 + wave * 16 + l15;   // A-fragment row for the GEMM
    __syncthreads();

    for (int t = 0; t < TSTEPS; ++t) {
        const int cur = t & 1, nxt = cur ^ 1;

        // prefetch xp (independent of h) and next mask
        float xr[4], xz[4], xn_[4], mnext[4];
#pragma unroll
        for (int i = 0; i < 4; ++i) {
            const size_t base = ((size_t)t * NBATCH + (nb0 + i)) * 3072 + j;
            xr[i]  = bf2f(xp[base]);
            xz[i]  = bf2f(xp[base + 1024]);
            xn_[i] = bf2f(xp[base + 2048]);
            mnext[i] = (t < TSTEPS - 1) ? mask_val(masks, mfmt, (t + 1) * NBATCH + nb0 + i) : 0.f;
        }

        const unsigned short* hhi_c = hhi + (size_t)cur * (NBATCH * HDIM);
        const unsigned short* hlo_c = hlo + (size_t)cur * (NBATCH * HDIM);

        f32x4 acc[3];
        const f32x4 zz = {0.f, 0.f, 0.f, 0.f};
        acc[0] = zz; acc[1] = zz; acc[2] = zz;

#pragma unroll 4
        for (int kt = 0; kt < 32; ++kt) {
            const int kb = kt * 32 + l4 * 8;
            const bf16x8 ah = *(const bf16x8*)(hhi_c + (size_t)an * 1024 + kb);
            const bf16x8 al = *(const bf16x8*)(hlo_c + (size_t)an * 1024 + kb);
#pragma unroll
            for (int ct = 0; ct < 3; ++ct) {
                const int sr = ct * 16 + l15;
                const int byte = (sr * 2048 + kt * 64 + l4 * 16) ^ ((sr & 7) << 4);
                const bf16x8 bw = *(const bf16x8*)((char*)Wl + byte);
                acc[ct] = __builtin_amdgcn_mfma_f32_16x16x32_bf16(ah, bw, acc[ct], 0, 0, 0);
                acc[ct] = __builtin_amdgcn_mfma_f32_16x16x32_bf16(al, bw, acc[ct], 0, 0, 0);
            }
        }

        // gates + update (all lane-local)
#pragma unroll
        for (int i = 0; i < 4; ++i) {
            const int n = nb0 + i;
            const float hr = acc[0][i] + bhr;
            const float hz = acc[1][i] + bhz;
            const float hn = acc[2][i] + bhn;
            const float r  = 1.f / (1.f + __expf(-(xr[i] + hr)));
            const float z  = 1.f / (1.f + __expf(-(xz[i] + hz)));
            const float nc = tanhf(xn_[i] + r * hn);
            const float hnew = (1.f - z) * nc + z * hold[i];
            out[((size_t)t * NBATCH + n) * HDIM + j] = hnew;
            if (t == TSTEPS - 1) {
                out[(size_t)TSTEPS * NBATCH * HDIM + (size_t)n * HDIM + j] = hnew;
            } else {
                const float hm = hnew * mnext[i];
                hold[i] = hm;
                const size_t ho = (size_t)nxt * (NBATCH * HDIM) + (size_t)n * HDIM + j;
                const unsigned short hi = f2bf(hm);
                hhi[ho] = hi;
                hlo[ho] = f2bf(hm - bf2f(hi));
            }
        }

        if (t != TSTEPS - 1) {
            __syncthreads();
            if (tid == 0) {
                __threadfence();
                int a = __hip_atomic_fetch_add(bar_ctr, 1, __ATOMIC_ACQ_REL, __HIP_MEMORY_SCOPE_AGENT);
                if (a == (int)gridDim.x - 1) {
                    __hip_atomic_store(bar_ctr, 0, __ATOMIC_RELAXED, __HIP_MEMORY_SCOPE_AGENT);
                    __hip_atomic_store(bar_gen, t + 1, __ATOMIC_RELEASE, __HIP_MEMORY_SCOPE_AGENT);
                } else {
                    while (__hip_atomic_load(bar_gen, __ATOMIC_ACQUIRE, __HIP_MEMORY_SCOPE_AGENT) < t + 1) {
                        __builtin_amdgcn_s_sleep(8);
                    }
                }
            }
            __syncthreads();
        }
    }
}

// ============== Fallback: round-2 monolithic kernel (ws too small) ==============
__launch_bounds__(256)
__global__ void gru_main(const float* __restrict__ x,
                         const unsigned char* __restrict__ masks,
                         const float* __restrict__ bih, const float* __restrict__ bhh,
                         const unsigned short* __restrict__ wih,
                         const unsigned short* __restrict__ whh,
                         float* __restrict__ out,
                         float* __restrict__ hf,
                         unsigned short* __restrict__ hhi,
                         unsigned short* __restrict__ hlo,
                         int* __restrict__ bar_ctr, int* __restrict__ bar_gen,
                         const int* __restrict__ mflag) {
    const int bid  = blockIdx.x;
    const int xcd  = bid & 7;
    const int slot = bid >> 3;
    const int cb   = xcd * 2 + (slot >> 2);
    const int rb   = slot & 3;
    const int tid  = threadIdx.x;
    const int wid  = tid >> 6;
    const int lane = tid & 63;
    const int l15  = lane & 15;
    const int l4   = lane >> 4;
    const int mfmt = *mflag;

    __shared__ float xp_l[32][196];
    __shared__ float hp_l[32][196];

    int gbase[3];
#pragma unroll
    for (int c = 0; c < 3; ++c) {
        int ct = wid * 3 + c;
        gbase[c] = (ct >> 2) * 1024 + cb * 64 + (ct & 3) * 16;
    }

    for (int t = 0; t < TSTEPS; ++t) {
        const int cur = t & 1, nxt = cur ^ 1;
        f32x4 accx[2][3], acch[2][3];
        const f32x4 zz = {0.f, 0.f, 0.f, 0.f};
#pragma unroll
        for (int rt = 0; rt < 2; ++rt)
#pragma unroll
            for (int c = 0; c < 3; ++c) { accx[rt][c] = zz; acch[rt][c] = zz; }

        const unsigned short* hhi_c = hhi + (size_t)cur * (NBATCH * HDIM);
        const unsigned short* hlo_c = hlo + (size_t)cur * (NBATCH * HDIM);

        for (int kk = 0; kk < DDIM; kk += 32) {
            const int kb = kk + l4 * 8;
            bf16x8 axh[2], axl[2], ahh[2], ahl[2];
#pragma unroll
            for (int rt = 0; rt < 2; ++rt) {
                const int row = rb * 32 + rt * 16 + l15;
                const float* px = x + ((size_t)(t * NBATCH + row)) * DDIM + kb;
                float4 f0 = *(const float4*)px;
                float4 f1 = *(const float4*)(px + 4);
                float v[8] = { f0.x, f0.y, f0.z, f0.w, f1.x, f1.y, f1.z, f1.w };
#pragma unroll
                for (int q = 0; q < 8; ++q) {
                    unsigned short hi = f2bf(v[q]);
                    axh[rt][q] = (short)hi;
                    axl[rt][q] = (short)f2bf(v[q] - bf2f(hi));
                }
                const size_t hoff = (size_t)row * HDIM + kb;
                ahh[rt] = *(const bf16x8*)(hhi_c + hoff);
                ahl[rt] = *(const bf16x8*)(hlo_c + hoff);
            }
#pragma unroll
            for (int c = 0; c < 3; ++c) {
                const size_t wrow = (size_t)(gbase[c] + l15) * 1024 + kb;
                const bf16x8 bx = *(const bf16x8*)(wih + wrow);
                const bf16x8 bh = *(const bf16x8*)(whh + wrow);
#pragma unroll
                for (int rt = 0; rt < 2; ++rt) {
                    accx[rt][c] = __builtin_amdgcn_mfma_f32_16x16x32_bf16(axh[rt], bx, accx[rt][c], 0, 0, 0);
                    accx[rt][c] = __builtin_amdgcn_mfma_f32_16x16x32_bf16(axl[rt], bx, accx[rt][c], 0, 0, 0);
                    acch[rt][c] = __builtin_amdgcn_mfma_f32_16x16x32_bf16(ahh[rt], bh, acch[rt][c], 0, 0, 0);
                    acch[rt][c] = __builtin_amdgcn_mfma_f32_16x16x32_bf16(ahl[rt], bh, acch[rt][c], 0, 0, 0);
                }
            }
        }

#pragma unroll
        for (int c = 0; c < 3; ++c) {
            const int ct = wid * 3 + c;
#pragma unroll
            for (int rt = 0; rt < 2; ++rt) {
#pragma unroll
                for (int i = 0; i < 4; ++i) {
                    const int row = rt * 16 + l4 * 4 + i;
                    const int col = ct * 16 + l15;
                    xp_l[row][col] = accx[rt][c][i];
                    hp_l[row][col] = acch[rt][c][i];
                }
            }
        }
        __syncthreads();

#pragma unroll
        for (int u = 0; u < 8; ++u) {
            const int o   = u * 256 + tid;
            const int row = o >> 6;
            const int jj  = o & 63;
            const int nIdx = rb * 32 + row;
            const int gj   = cb * 64 + jj;
            const float xr = xp_l[row][jj],       hr = hp_l[row][jj];
            const float xz = xp_l[row][64 + jj],  hz = hp_l[row][64 + jj];
            const float xn = xp_l[row][128 + jj], hn = hp_l[row][128 + jj];
            const float ar = xr + hr + bih[gj] + bhh[gj];
            const float az = xz + hz + bih[1024 + gj] + bhh[1024 + gj];
            const float rg = 1.f / (1.f + __expf(-ar));
            const float zg = 1.f / (1.f + __expf(-az));
            const float nc = tanhf(xn + bih[2048 + gj] + rg * (hn + bhh[2048 + gj]));
            const float hold = hf[(size_t)cur * (NBATCH * HDIM) + (size_t)nIdx * HDIM + gj];
            const float hnew = (1.f - zg) * nc + zg * hold;
            out[((size_t)t * NBATCH + nIdx) * HDIM + gj] = hnew;
            if (t == TSTEPS - 1) {
                out[(size_t)TSTEPS * NBATCH * HDIM + (size_t)nIdx * HDIM + gj] = hnew;
            } else {
                const float m  = mask_val(masks, mfmt, (t + 1) * NBATCH + nIdx);
                const float hm = hnew * m;
                const size_t ho = (size_t)nxt * (NBATCH * HDIM) + (size_t)nIdx * HDIM + gj;
                hf[ho] = hm;
                const unsigned short hi = f2bf(hm);
                hhi[ho] = hi;
                hlo[ho] = f2bf(hm - bf2f(hi));
            }
        }

        if (t != TSTEPS - 1) {
            __syncthreads();
            if (tid == 0) {
                __threadfence();
                int a = __hip_atomic_fetch_add(bar_ctr, 1, __ATOMIC_ACQ_REL, __HIP_MEMORY_SCOPE_AGENT);
                if (a == (int)gridDim.x - 1) {
                    __hip_atomic_store(bar_ctr, 0, __ATOMIC_RELAXED, __HIP_MEMORY_SCOPE_AGENT);
                    __hip_atomic_store(bar_gen, t + 1, __ATOMIC_RELEASE, __HIP_MEMORY_SCOPE_AGENT);
                } else {
                    while (__hip_atomic_load(bar_gen, __ATOMIC_ACQUIRE, __HIP_MEMORY_SCOPE_AGENT) < t + 1) {
                        __builtin_amdgcn_s_sleep(16);
                    }
                }
            }
            __syncthreads();
        }
    }
}

extern "C" void kernel_launch(void* const* d_in, const int* in_sizes, int n_in,
                              void* d_out, int out_size, void* d_ws, size_t ws_size,
                              hipStream_t stream) {
    const float* x      = (const float*)d_in[0];
    const float* hidden = (const float*)d_in[1];
    const unsigned char* masks = (const unsigned char*)d_in[2];
    const float* wih    = (const float*)d_in[3];
    const float* whh    = (const float*)d_in[4];
    const float* bih    = (const float*)d_in[5];
    const float* bhh    = (const float*)d_in[6];
    float* out = (float*)d_out;
    char*  ws  = (char*)d_ws;

    hipMemsetAsync(ws, 0, 512, stream);
    detect_mask<<<1, 256, 0, stream>>>(masks, (int*)(ws + MFLAG_OFF));
    conv_w<<<3072, 256, 0, stream>>>(wih, whh,
                                     (unsigned short*)(ws + WIH_OFF),
                                     (unsigned short*)(ws + WHH_OFF));
    init_h<<<128, 256, 0, stream>>>(hidden, masks, (const int*)(ws + MFLAG_OFF),
                                    (float*)(ws + HF_OFF),
                                    (unsigned short*)(ws + HHI_OFF),
                                    (unsigned short*)(ws + HLO_OFF));

    if (ws_size >= (size_t)WS_NEED) {
        conv_x<<<16384, 256, 0, stream>>>(x, (unsigned short*)(ws + XB_OFF));
        xproj_gemm<<<dim3(256, 24), 256, 0, stream>>>((const unsigned short*)(ws + XB_OFF),
                                                      (const unsigned short*)(ws + WIH_OFF),
                                                      bih,
                                                      (unsigned short*)(ws + XP_OFF));
        gru_seq<<<128, 256, 0, stream>>>((const unsigned short*)(ws + XP_OFF),
                                         masks,
                                         (const int*)(ws + MFLAG_OFF),
                                         bhh,
                                         (const unsigned short*)(ws + WHH_OFF),
                                         hidden,
                                         out,
                                         (unsigned short*)(ws + HHI_OFF),
                                         (unsigned short*)(ws + HLO_OFF),
                                         (int*)(ws + BAR_CTR_OFF), (int*)(ws + BAR_GEN_OFF));
    } else {
        gru_main<<<64, 256, 0, stream>>>(x, masks, bih, bhh,
                                         (const unsigned short*)(ws + WIH_OFF),
                                         (const unsigned short*)(ws + WHH_OFF),
                                         out,
                                         (float*)(ws + HF_OFF),
                                         (unsigned short*)(ws + HHI_OFF),
                                         (unsigned short*)(ws + HLO_OFF),
                                         (int*)(ws + BAR_CTR_OFF), (int*)(ws + BAR_GEN_OFF),
                                         (const int*)(ws + MFLAG_OFF));
    }
}

// Round 4
// 5294.201 us; speedup vs baseline: 2.8878x; 1.1145x over previous
//
#include <hip/hip_runtime.h>

// Masked GRU (RNNStateEncoder), T=256, N=128, D=H=1024.
// Phase A: x-projection GEMM (f32 in, bf16 MFMA, LDS dbuf), t-ordered tiles,
//          per-tile progress counters -> overlaps with Phase B.
// Phase B: sequential h-GEMM, W_hh LDS-resident, 128 WGs, flag-array grid
//          barrier (relaxed polls + single acquire per step), h hi/lo bf16.
// Fallback (ws too small): round-2 monolithic persistent kernel.

#define TSTEPS 256
#define NBATCH 128
#define DDIM   1024
#define HDIM   1024

typedef short  bf16x8 __attribute__((ext_vector_type(8)));
typedef float  f32x4  __attribute__((ext_vector_type(4)));

// ---- ws layout (bytes) ----
#define BAR_CTR_OFF  0                          // fallback barrier counter
#define BAR_GEN_OFF  4                          // fallback + fast 'gen'
#define MFLAG_OFF    8
#define FLAGS_OFF    1024                       // 128 u32 arrival flags
#define XPROG_OFF    2048                       // 256 u32 xproj progress
#define WIH_OFF      8192
#define WHH_OFF      (WIH_OFF + 6291456)        // 6299648
#define HF_OFF       (WHH_OFF + 6291456)        // 12591104 : float h[2][128*1024] (fallback)
#define HHI_OFF      (HF_OFF + 1048576)         // 13639680 : ushort hhi[2][128*1024]
#define HLO_OFF      (HHI_OFF + 524288)         // 14163968 : ushort hlo[2][128*1024]
#define XP_OFF       (HLO_OFF + 524288)         // 14688256 : ushort xp[32768*3072]
#define WS_NEED      (XP_OFF + 201326592ull)    // 216014848

#define SCOPE_AGENT __HIP_MEMORY_SCOPE_AGENT

__device__ __forceinline__ unsigned short f2bf(float f) {
    union { float f; unsigned u; } v; v.f = f;
    unsigned r = v.u + 0x7FFFu + ((v.u >> 16) & 1u);   // RNE
    return (unsigned short)(r >> 16);
}
__device__ __forceinline__ float bf2f(unsigned short h) {
    union { unsigned u; float f; } v; v.u = ((unsigned)h) << 16;
    return v.f;
}

__device__ __forceinline__ float mask_val(const void* m, int fmt, int idx) {
    if (fmt == 0) return ((const unsigned char*)m)[idx] ? 1.f : 0.f;
    if (fmt == 1) return ((const int*)m)[idx] ? 1.f : 0.f;
    return (((const float*)m)[idx] != 0.f) ? 1.f : 0.f;
}

// ---- detect mask dtype: 0 = bool bytes, 1 = int32, 2 = float32 ----
__global__ void detect_mask(const unsigned char* __restrict__ m8, int* __restrict__ flag) {
    __shared__ int s_ones, s_c01, s_cf;
    if (threadIdx.x == 0) { s_ones = 0; s_c01 = 0; s_cf = 0; }
    __syncthreads();
    int ones = 0;
    for (int i = threadIdx.x; i < 4096; i += 256) ones += (m8[i] == 1);
    int c01 = 0, cf = 0;
    const unsigned* m32 = (const unsigned*)m8;
    for (int i = threadIdx.x; i < 1024; i += 256) {
        unsigned v = m32[i];
        c01 += (v <= 1u);
        cf  += (v == 0u || v == 0x3F800000u);
    }
    atomicAdd(&s_ones, ones); atomicAdd(&s_c01, c01); atomicAdd(&s_cf, cf);
    __syncthreads();
    if (threadIdx.x == 0) *flag = (s_ones > 2048) ? 0 : ((s_c01 >= s_cf) ? 1 : 2);
}

// ---- convert both weight matrices to bf16 (row-major (3072,1024)) ----
__global__ void conv_w(const float* __restrict__ wih, const float* __restrict__ whh,
                       unsigned short* __restrict__ wih_b, unsigned short* __restrict__ whh_b) {
    size_t i = ((size_t)blockIdx.x * 256 + threadIdx.x) * 4;
    if (i >= (size_t)3145728) return;
    float4 a = *(const float4*)(wih + i);
    ushort4 ra; ra.x = f2bf(a.x); ra.y = f2bf(a.y); ra.z = f2bf(a.z); ra.w = f2bf(a.w);
    *(ushort4*)(wih_b + i) = ra;
    float4 b = *(const float4*)(whh + i);
    ushort4 rb; rb.x = f2bf(b.x); rb.y = f2bf(b.y); rb.z = f2bf(b.z); rb.w = f2bf(b.w);
    *(ushort4*)(whh_b + i) = rb;
}

// ---- init h0 (pre-masked with m[0]) into buffer 0 ----
__global__ void init_h(const float* __restrict__ h0, const unsigned char* __restrict__ masks,
                       const int* __restrict__ flag,
                       float* __restrict__ hf, unsigned short* __restrict__ hhi,
                       unsigned short* __restrict__ hlo) {
    int i = (blockIdx.x * 256 + threadIdx.x) * 4;
    if (i >= NBATCH * HDIM) return;
    int fmt = *flag;
    int n = i >> 10;
    float m = mask_val(masks, fmt, n);
    float4 a = *(const float4*)(h0 + i);
    float v[4] = { a.x * m, a.y * m, a.z * m, a.w * m };
#pragma unroll
    for (int q = 0; q < 4; ++q) {
        hf[i + q] = v[q];
        unsigned short hi = f2bf(v[q]);
        hhi[i + q] = hi;
        hlo[i + q] = f2bf(v[q] - bf2f(hi));
    }
}

// ============== Phase A: xp = bf16(x) @ W_ih^T + b_ih  (bf16 out) ==============
// grid(24, 256): x = n-block (gate cols), y = m-block == time step t.
// t-tiles complete in increasing-t order; each block release-adds xprog[t].
__launch_bounds__(256)
__global__ void xproj_gemm(const float* __restrict__ x,
                           const unsigned short* __restrict__ wih_b,
                           const float* __restrict__ bih,
                           unsigned short* __restrict__ xp,
                           unsigned* __restrict__ xprog) {
    const int n0 = blockIdx.x * 128;     // gate cols
    const int m0 = blockIdx.y * 128;     // rows (= t * NBATCH)
    const int tid  = threadIdx.x;
    const int wave = tid >> 6;
    const int lane = tid & 63;
    const int l15  = lane & 15;
    const int l4   = lane >> 4;
    const int wr   = wave >> 1;
    const int wc   = wave & 1;

    __shared__ __align__(16) unsigned short Asm[2][4096];   // [128][32]
    __shared__ __align__(16) unsigned short Bsm[2][4096];

    const int row0 = tid >> 2, kc0 = tid & 3;
    const int wb0 = ((row0 * 64 + kc0 * 16) ^ ((row0 & 7) << 4));
    const int wb1 = (((row0 + 64) * 64 + kc0 * 16) ^ (((row0 + 64) & 7) << 4));

    f32x4 acc[4][4];
    const f32x4 zz = {0.f, 0.f, 0.f, 0.f};
#pragma unroll
    for (int m = 0; m < 4; ++m)
#pragma unroll
        for (int n = 0; n < 4; ++n) acc[m][n] = zz;

    // stage A-chunk from f32 x, convert to bf16 in regs
    auto ldA = [&](int row, int kk) -> bf16x8 {
        const float* p = x + (size_t)(m0 + row) * 1024 + kk + kc0 * 8;
        float4 u0 = *(const float4*)p;
        float4 u1 = *(const float4*)(p + 4);
        bf16x8 r;
        r[0] = (short)f2bf(u0.x); r[1] = (short)f2bf(u0.y);
        r[2] = (short)f2bf(u0.z); r[3] = (short)f2bf(u0.w);
        r[4] = (short)f2bf(u1.x); r[5] = (short)f2bf(u1.y);
        r[6] = (short)f2bf(u1.z); r[7] = (short)f2bf(u1.w);
        return r;
    };

    {
        bf16x8 a0 = ldA(row0, 0);
        bf16x8 a1 = ldA(row0 + 64, 0);
        bf16x8 b0 = *(const bf16x8*)(wih_b + (size_t)(n0 + row0) * 1024 + kc0 * 8);
        bf16x8 b1 = *(const bf16x8*)(wih_b + (size_t)(n0 + row0 + 64) * 1024 + kc0 * 8);
        *(bf16x8*)((char*)Asm[0] + wb0) = a0;
        *(bf16x8*)((char*)Asm[0] + wb1) = a1;
        *(bf16x8*)((char*)Bsm[0] + wb0) = b0;
        *(bf16x8*)((char*)Bsm[0] + wb1) = b1;
    }
    __syncthreads();

    for (int kt = 0; kt < 32; ++kt) {
        const int cur = kt & 1;
        bf16x8 a0, a1, b0, b1;
        const bool pre = (kt < 31);
        if (pre) {
            const int kk = (kt + 1) * 32;
            a0 = ldA(row0, kk);
            a1 = ldA(row0 + 64, kk);
            b0 = *(const bf16x8*)(wih_b + (size_t)(n0 + row0) * 1024 + kk + kc0 * 8);
            b1 = *(const bf16x8*)(wih_b + (size_t)(n0 + row0 + 64) * 1024 + kk + kc0 * 8);
        }
        bf16x8 af[4], bfr[4];
#pragma unroll
        for (int m = 0; m < 4; ++m) {
            const int r = wr * 64 + m * 16 + l15;
            af[m] = *(const bf16x8*)((char*)Asm[cur] + ((r * 64 + l4 * 16) ^ ((r & 7) << 4)));
        }
#pragma unroll
        for (int n = 0; n < 4; ++n) {
            const int r = wc * 64 + n * 16 + l15;
            bfr[n] = *(const bf16x8*)((char*)Bsm[cur] + ((r * 64 + l4 * 16) ^ ((r & 7) << 4)));
        }
#pragma unroll
        for (int m = 0; m < 4; ++m)
#pragma unroll
            for (int n = 0; n < 4; ++n)
                acc[m][n] = __builtin_amdgcn_mfma_f32_16x16x32_bf16(af[m], bfr[n], acc[m][n], 0, 0, 0);
        if (pre) {
            const int nxt = cur ^ 1;
            *(bf16x8*)((char*)Asm[nxt] + wb0) = a0;
            *(bf16x8*)((char*)Asm[nxt] + wb1) = a1;
            *(bf16x8*)((char*)Bsm[nxt] + wb0) = b0;
            *(bf16x8*)((char*)Bsm[nxt] + wb1) = b1;
        }
        __syncthreads();
    }

#pragma unroll
    for (int n = 0; n < 4; ++n) {
        const int col = n0 + wc * 64 + n * 16 + l15;
        const float bv = bih[col];
#pragma unroll
        for (int m = 0; m < 4; ++m) {
#pragma unroll
            for (int i = 0; i < 4; ++i) {
                const int row = m0 + wr * 64 + m * 16 + l4 * 4 + i;
                xp[(size_t)row * 3072 + col] = f2bf(acc[m][n][i] + bv);
            }
        }
    }

    __syncthreads();   // all stores complete-to-L2 (waitcnt before barrier)
    if (tid == 0)
        __hip_atomic_fetch_add(&xprog[blockIdx.y], 1u, __ATOMIC_RELEASE, SCOPE_AGENT);
}

// ============== Phase B: sequential GRU steps ==============
// 128 WGs = 64 col-blocks (16 h-cols) x 2 row-blocks (64 rows), 4 waves.
// Flag-array grid barrier: release flag store, WG0 watches, relaxed gen poll +
// single acquire. xp/mask prefetch overlaps the barrier wait.
__launch_bounds__(256)
__global__ void gru_seq(const unsigned short* __restrict__ xp,
                        const unsigned char* __restrict__ masks,
                        const int* __restrict__ mflag,
                        const float* __restrict__ bhh,
                        const unsigned short* __restrict__ whh_b,
                        const float* __restrict__ h0,
                        float* __restrict__ out,
                        unsigned short* __restrict__ hhi,
                        unsigned short* __restrict__ hlo,
                        unsigned* flags, unsigned* gen, unsigned* xprog) {
    const int bid = blockIdx.x;
    const int cb  = bid >> 1;          // 0..63
    const int rb  = bid & 1;           // 0..1
    const int tid = threadIdx.x;
    const int wave = tid >> 6;
    const int lane = tid & 63;
    const int l15  = lane & 15;
    const int l4   = lane >> 4;
    const int mfmt = *mflag;

    __shared__ __align__(16) unsigned short Wl[49152];   // 48 rows x 1024, swizzled

#pragma unroll
    for (int it = 0; it < 24; ++it) {
        const int c  = it * 256 + tid;
        const int sr = c >> 7;
        const int kc = c & 127;
        const int g  = (sr >> 4) * 1024 + cb * 16 + (sr & 15);
        bf16x8 v = *(const bf16x8*)(whh_b + (size_t)g * 1024 + kc * 8);
        const int byte = (sr * 2048 + kc * 16) ^ ((sr & 7) << 4);
        *(bf16x8*)((char*)Wl + byte) = v;
    }

    const int j   = cb * 16 + l15;
    const int nb0 = rb * 64 + wave * 16 + l4 * 4;
    const int an  = rb * 64 + wave * 16 + l15;
    const float bhr = bhh[j], bhz = bhh[1024 + j], bhn = bhh[2048 + j];

    float hold[4];
#pragma unroll
    for (int i = 0; i < 4; ++i) {
        const int n = nb0 + i;
        hold[i] = h0[(size_t)n * 1024 + j] * mask_val(masks, mfmt, n);
    }

    // wait for xp tile 0, then prefetch xp[0] and store-mask for t=0
    if (tid == 0) {
        while (__hip_atomic_load(&xprog[0], __ATOMIC_RELAXED, SCOPE_AGENT) < 24u)
            __builtin_amdgcn_s_sleep(2);
    }
    __syncthreads();   // also joins the Wl staging

    float xr[4], xz[4], xn_[4], mn[4];
#pragma unroll
    for (int i = 0; i < 4; ++i) {
        const size_t base = (size_t)(nb0 + i) * 3072 + j;
        xr[i]  = bf2f(xp[base]);
        xz[i]  = bf2f(xp[base + 1024]);
        xn_[i] = bf2f(xp[base + 2048]);
        mn[i]  = mask_val(masks, mfmt, NBATCH + nb0 + i);
    }

    for (int t = 0; t < TSTEPS; ++t) {
        const int cur = t & 1, nxt = cur ^ 1;
        const unsigned short* hhi_c = hhi + (size_t)cur * (NBATCH * HDIM);
        const unsigned short* hlo_c = hlo + (size_t)cur * (NBATCH * HDIM);

        f32x4 acc[3];
        const f32x4 zz = {0.f, 0.f, 0.f, 0.f};
        acc[0] = zz; acc[1] = zz; acc[2] = zz;

#pragma unroll 4
        for (int kt = 0; kt < 32; ++kt) {
            const int kb = kt * 32 + l4 * 8;
            const bf16x8 ah = *(const bf16x8*)(hhi_c + (size_t)an * 1024 + kb);
            const bf16x8 al = *(const bf16x8*)(hlo_c + (size_t)an * 1024 + kb);
#pragma unroll
            for (int ct = 0; ct < 3; ++ct) {
                const int sr = ct * 16 + l15;
                const int byte = (sr * 2048 + kt * 64 + l4 * 16) ^ ((sr & 7) << 4);
                const bf16x8 bw = *(const bf16x8*)((char*)Wl + byte);
                acc[ct] = __builtin_amdgcn_mfma_f32_16x16x32_bf16(ah, bw, acc[ct], 0, 0, 0);
                acc[ct] = __builtin_amdgcn_mfma_f32_16x16x32_bf16(al, bw, acc[ct], 0, 0, 0);
            }
        }

        // gates + update (lane-local)
#pragma unroll
        for (int i = 0; i < 4; ++i) {
            const int n = nb0 + i;
            const float hr = acc[0][i] + bhr;
            const float hz = acc[1][i] + bhz;
            const float hn = acc[2][i] + bhn;
            const float r  = 1.f / (1.f + __expf(-(xr[i] + hr)));
            const float z  = 1.f / (1.f + __expf(-(xz[i] + hz)));
            const float nc = tanhf(xn_[i] + r * hn);
            const float hnew = (1.f - z) * nc + z * hold[i];
            out[((size_t)t * NBATCH + n) * HDIM + j] = hnew;
            if (t == TSTEPS - 1) {
                out[(size_t)TSTEPS * NBATCH * HDIM + (size_t)n * HDIM + j] = hnew;
            } else {
                const float hm = hnew * mn[i];
                hold[i] = hm;
                const size_t ho = (size_t)nxt * (NBATCH * HDIM) + (size_t)n * HDIM + j;
                const unsigned short hi = f2bf(hm);
                hhi[ho] = hi;
                hlo[ho] = f2bf(hm - bf2f(hi));
            }
        }

        if (t < TSTEPS - 1) {
            // all waves' h stores complete-to-L2, then one release (wbl2) signal
            __syncthreads();
            if (tid == 0)
                __hip_atomic_store(&flags[bid], (unsigned)(t + 1), __ATOMIC_RELEASE, SCOPE_AGENT);

            // overlap barrier wait: gate on xp tile t+1 then prefetch regs
            if (tid == 0) {
                while (__hip_atomic_load(&xprog[t + 1], __ATOMIC_RELAXED, SCOPE_AGENT) < 24u)
                    __builtin_amdgcn_s_sleep(2);
            }
            __syncthreads();
#pragma unroll
            for (int i = 0; i < 4; ++i) {
                const size_t base = ((size_t)(t + 1) * NBATCH + (nb0 + i)) * 3072 + j;
                xr[i]  = bf2f(xp[base]);
                xz[i]  = bf2f(xp[base + 1024]);
                xn_[i] = bf2f(xp[base + 2048]);
                mn[i]  = (t + 2 < TSTEPS) ? mask_val(masks, mfmt, (t + 2) * NBATCH + nb0 + i) : 0.f;
            }

            if (bid == 0) {
                if (tid < 128) {
                    while (__hip_atomic_load(&flags[tid], __ATOMIC_RELAXED, SCOPE_AGENT) < (unsigned)(t + 1))
                        __builtin_amdgcn_s_sleep(2);
                }
                __syncthreads();
                if (tid == 0)
                    __hip_atomic_store(gen, (unsigned)(t + 1), __ATOMIC_RELEASE, SCOPE_AGENT);
            }
            if (tid == 0) {
                while (__hip_atomic_load(gen, __ATOMIC_RELAXED, SCOPE_AGENT) < (unsigned)(t + 1))
                    __builtin_amdgcn_s_sleep(2);
                (void)__hip_atomic_load(gen, __ATOMIC_ACQUIRE, SCOPE_AGENT);  // single L2 inv
            }
            __syncthreads();
        }
    }
}

// ============== Fallback: round-2 monolithic kernel (ws too small) ==============
__launch_bounds__(256)
__global__ void gru_main(const float* __restrict__ x,
                         const unsigned char* __restrict__ masks,
                         const float* __restrict__ bih, const float* __restrict__ bhh,
                         const unsigned short* __restrict__ wih,
                         const unsigned short* __restrict__ whh,
                         float* __restrict__ out,
                         float* __restrict__ hf,
                         unsigned short* __restrict__ hhi,
                         unsigned short* __restrict__ hlo,
                         int* __restrict__ bar_ctr, int* __restrict__ bar_gen,
                         const int* __restrict__ mflag) {
    const int bid  = blockIdx.x;
    const int xcd  = bid & 7;
    const int slot = bid >> 3;
    const int cb   = xcd * 2 + (slot >> 2);
    const int rb   = slot & 3;
    const int tid  = threadIdx.x;
    const int wid  = tid >> 6;
    const int lane = tid & 63;
    const int l15  = lane & 15;
    const int l4   = lane >> 4;
    const int mfmt = *mflag;

    __shared__ float xp_l[32][196];
    __shared__ float hp_l[32][196];

    int gbase[3];
#pragma unroll
    for (int c = 0; c < 3; ++c) {
        int ct = wid * 3 + c;
        gbase[c] = (ct >> 2) * 1024 + cb * 64 + (ct & 3) * 16;
    }

    for (int t = 0; t < TSTEPS; ++t) {
        const int cur = t & 1, nxt = cur ^ 1;
        f32x4 accx[2][3], acch[2][3];
        const f32x4 zz = {0.f, 0.f, 0.f, 0.f};
#pragma unroll
        for (int rt = 0; rt < 2; ++rt)
#pragma unroll
            for (int c = 0; c < 3; ++c) { accx[rt][c] = zz; acch[rt][c] = zz; }

        const unsigned short* hhi_c = hhi + (size_t)cur * (NBATCH * HDIM);
        const unsigned short* hlo_c = hlo + (size_t)cur * (NBATCH * HDIM);

        for (int kk = 0; kk < DDIM; kk += 32) {
            const int kb = kk + l4 * 8;
            bf16x8 axh[2], axl[2], ahh[2], ahl[2];
#pragma unroll
            for (int rt = 0; rt < 2; ++rt) {
                const int row = rb * 32 + rt * 16 + l15;
                const float* px = x + ((size_t)(t * NBATCH + row)) * DDIM + kb;
                float4 f0 = *(const float4*)px;
                float4 f1 = *(const float4*)(px + 4);
                float v[8] = { f0.x, f0.y, f0.z, f0.w, f1.x, f1.y, f1.z, f1.w };
#pragma unroll
                for (int q = 0; q < 8; ++q) {
                    unsigned short hi = f2bf(v[q]);
                    axh[rt][q] = (short)hi;
                    axl[rt][q] = (short)f2bf(v[q] - bf2f(hi));
                }
                const size_t hoff = (size_t)row * HDIM + kb;
                ahh[rt] = *(const bf16x8*)(hhi_c + hoff);
                ahl[rt] = *(const bf16x8*)(hlo_c + hoff);
            }
#pragma unroll
            for (int c = 0; c < 3; ++c) {
                const size_t wrow = (size_t)(gbase[c] + l15) * 1024 + kb;
                const bf16x8 bx = *(const bf16x8*)(wih + wrow);
                const bf16x8 bh = *(const bf16x8*)(whh + wrow);
#pragma unroll
                for (int rt = 0; rt < 2; ++rt) {
                    accx[rt][c] = __builtin_amdgcn_mfma_f32_16x16x32_bf16(axh[rt], bx, accx[rt][c], 0, 0, 0);
                    accx[rt][c] = __builtin_amdgcn_mfma_f32_16x16x32_bf16(axl[rt], bx, accx[rt][c], 0, 0, 0);
                    acch[rt][c] = __builtin_amdgcn_mfma_f32_16x16x32_bf16(ahh[rt], bh, acch[rt][c], 0, 0, 0);
                    acch[rt][c] = __builtin_amdgcn_mfma_f32_16x16x32_bf16(ahl[rt], bh, acch[rt][c], 0, 0, 0);
                }
            }
        }

#pragma unroll
        for (int c = 0; c < 3; ++c) {
            const int ct = wid * 3 + c;
#pragma unroll
            for (int rt = 0; rt < 2; ++rt) {
#pragma unroll
                for (int i = 0; i < 4; ++i) {
                    const int row = rt * 16 + l4 * 4 + i;
                    const int col = ct * 16 + l15;
                    xp_l[row][col] = accx[rt][c][i];
                    hp_l[row][col] = acch[rt][c][i];
                }
            }
        }
        __syncthreads();

#pragma unroll
        for (int u = 0; u < 8; ++u) {
            const int o   = u * 256 + tid;
            const int row = o >> 6;
            const int jj  = o & 63;
            const int nIdx = rb * 32 + row;
            const int gj   = cb * 64 + jj;
            const float xr = xp_l[row][jj],       hr = hp_l[row][jj];
            const float xz = xp_l[row][64 + jj],  hz = hp_l[row][64 + jj];
            const float xn = xp_l[row][128 + jj], hn = hp_l[row][128 + jj];
            const float ar = xr + hr + bih[gj] + bhh[gj];
            const float az = xz + hz + bih[1024 + gj] + bhh[1024 + gj];
            const float rg = 1.f / (1.f + __expf(-ar));
            const float zg = 1.f / (1.f + __expf(-az));
            const float nc = tanhf(xn + bih[2048 + gj] + rg * (hn + bhh[2048 + gj]));
            const float hold = hf[(size_t)cur * (NBATCH * HDIM) + (size_t)nIdx * HDIM + gj];
            const float hnew = (1.f - zg) * nc + zg * hold;
            out[((size_t)t * NBATCH + nIdx) * HDIM + gj] = hnew;
            if (t == TSTEPS - 1) {
                out[(size_t)TSTEPS * NBATCH * HDIM + (size_t)nIdx * HDIM + gj] = hnew;
            } else {
                const float m  = mask_val(masks, mfmt, (t + 1) * NBATCH + nIdx);
                const float hm = hnew * m;
                const size_t ho = (size_t)nxt * (NBATCH * HDIM) + (size_t)nIdx * HDIM + gj;
                hf[ho] = hm;
                const unsigned short hi = f2bf(hm);
                hhi[ho] = hi;
                hlo[ho] = f2bf(hm - bf2f(hi));
            }
        }

        if (t != TSTEPS - 1) {
            __syncthreads();
            if (tid == 0) {
                __threadfence();
                int a = __hip_atomic_fetch_add(bar_ctr, 1, __ATOMIC_ACQ_REL, SCOPE_AGENT);
                if (a == (int)gridDim.x - 1) {
                    __hip_atomic_store(bar_ctr, 0, __ATOMIC_RELAXED, SCOPE_AGENT);
                    __hip_atomic_store(bar_gen, t + 1, __ATOMIC_RELEASE, SCOPE_AGENT);
                } else {
                    while (__hip_atomic_load(bar_gen, __ATOMIC_ACQUIRE, SCOPE_AGENT) < t + 1) {
                        __builtin_amdgcn_s_sleep(16);
                    }
                }
            }
            __syncthreads();
        }
    }
}

extern "C" void kernel_launch(void* const* d_in, const int* in_sizes, int n_in,
                              void* d_out, int out_size, void* d_ws, size_t ws_size,
                              hipStream_t stream) {
    const float* x      = (const float*)d_in[0];
    const float* hidden = (const float*)d_in[1];
    const unsigned char* masks = (const unsigned char*)d_in[2];
    const float* wih    = (const float*)d_in[3];
    const float* whh    = (const float*)d_in[4];
    const float* bih    = (const float*)d_in[5];
    const float* bhh    = (const float*)d_in[6];
    float* out = (float*)d_out;
    char*  ws  = (char*)d_ws;

    hipMemsetAsync(ws, 0, 4096, stream);
    detect_mask<<<1, 256, 0, stream>>>(masks, (int*)(ws + MFLAG_OFF));
    conv_w<<<3072, 256, 0, stream>>>(wih, whh,
                                     (unsigned short*)(ws + WIH_OFF),
                                     (unsigned short*)(ws + WHH_OFF));
    init_h<<<128, 256, 0, stream>>>(hidden, masks, (const int*)(ws + MFLAG_OFF),
                                    (float*)(ws + HF_OFF),
                                    (unsigned short*)(ws + HHI_OFF),
                                    (unsigned short*)(ws + HLO_OFF));

    if (ws_size >= (size_t)WS_NEED) {
        xproj_gemm<<<dim3(24, 256), 256, 0, stream>>>(x,
                                                      (const unsigned short*)(ws + WIH_OFF),
                                                      bih,
                                                      (unsigned short*)(ws + XP_OFF),
                                                      (unsigned*)(ws + XPROG_OFF));
        gru_seq<<<128, 256, 0, stream>>>((const unsigned short*)(ws + XP_OFF),
                                         masks,
                                         (const int*)(ws + MFLAG_OFF),
                                         bhh,
                                         (const unsigned short*)(ws + WHH_OFF),
                                         hidden,
                                         out,
                                         (unsigned short*)(ws + HHI_OFF),
                                         (unsigned short*)(ws + HLO_OFF),
                                         (unsigned*)(ws + FLAGS_OFF),
                                         (unsigned*)(ws + BAR_GEN_OFF),
                                         (unsigned*)(ws + XPROG_OFF));
    } else {
        gru_main<<<64, 256, 0, stream>>>(x, masks, bih, bhh,
                                         (const unsigned short*)(ws + WIH_OFF),
                                         (const unsigned short*)(ws + WHH_OFF),
                                         out,
                                         (float*)(ws + HF_OFF),
                                         (unsigned short*)(ws + HHI_OFF),
                                         (unsigned short*)(ws + HLO_OFF),
                                         (int*)(ws + BAR_CTR_OFF), (int*)(ws + BAR_GEN_OFF),
                                         (const int*)(ws + MFLAG_OFF));
    }
}